// Round 1
// baseline (520.940 us; speedup 1.0000x reference)
//
#include <hip/hip_runtime.h>

#define DIMQ 65536
#define BQ 128

// ---------------------------------------------------------------------------
// CNOT ring as an index permutation.
// Program order (wire space): C(0,1),C(1,2),...,C(14,15),C(15,0).
// Wire w <-> bit (15-w). In bit space the ops are (bc,bt) = (15,14),(14,13),
// ..., (1,0), (0,15), each: x ^= ((x>>bc)&1) << bt, applied sequentially.
// For a value held at pre-ring physical index x, its post-ring index is
// obtained by applying these maps to x in program order (verified on toys).
// The map is GF(2)-linear.
// ---------------------------------------------------------------------------
__host__ __device__ constexpr unsigned ring_map(unsigned x) {
  for (int bc = 15; bc >= 1; --bc) x ^= ((x >> bc) & 1u) << (bc - 1);
  x ^= (x & 1u) << 15;
  return x;
}

struct RBTab { unsigned v[64]; };
__host__ __device__ constexpr RBTab make_rb() {
  RBTab t{};
  for (int l = 0; l < 64; ++l) t.v[l] = ring_map(((unsigned)l) << 10);
  return t;
}
__device__ constexpr RBTab RB = make_rb();

// Fused U = RZ(phi) @ RY(theta) coefficients (complex 2x2), wave-uniform.
struct U2 { float r00, i00, r01, i01, r10, i10, r11, i11; };

__device__ inline U2 make_u(const float* params, int d, int w) {
  float th = 0.5f * params[(d * 16 + w) * 2 + 0];
  float ph = 0.5f * params[(d * 16 + w) * 2 + 1];
  float st, ct, sp, cp;
  sincosf(th, &st, &ct);
  sincosf(ph, &sp, &cp);
  // em = exp(-i*ph) = (cp, -sp); ep = conj(em)
  U2 u;
  u.r00 =  cp * ct; u.i00 = -sp * ct;   // em*cth
  u.r01 = -cp * st; u.i01 =  sp * st;   // -em*sth
  u.r10 =  cp * st; u.i10 =  sp * st;   // ep*sth
  u.r11 =  cp * ct; u.i11 =  sp * ct;   // ep*cth
  return u;
}

// In-register gate on local bit K of the 64-amplitude tile.
template <int K>
__device__ inline void apply_gate(float2 (&a)[64], const U2 u) {
#pragma unroll
  for (int l = 0; l < 64; ++l) {
    if (l & (1 << K)) continue;
    const int p = l | (1 << K);
    const float a0r = a[l].x, a0i = a[l].y, a1r = a[p].x, a1i = a[p].y;
    a[l].x = fmaf(u.r00, a0r, fmaf(-u.i00, a0i, fmaf(u.r01, a1r, -u.i01 * a1i)));
    a[l].y = fmaf(u.r00, a0i, fmaf( u.i00, a0r, fmaf(u.r01, a1i,  u.i01 * a1r)));
    a[p].x = fmaf(u.r10, a0r, fmaf(-u.i10, a0i, fmaf(u.r11, a1r, -u.i11 * a1i)));
    a[p].y = fmaf(u.r10, a0i, fmaf( u.i10, a0r, fmaf(u.r11, a1i,  u.i11 * a1r)));
  }
}

// ---------------------------------------------------------------------------
// Pass type 0: window bits 0..5 (wires 15..10). FIRST also does the
// [batch][dim] -> [dim][batch] transpose with im=0.
// ---------------------------------------------------------------------------
template <bool FIRST>
__global__ __launch_bounds__(128, 2)
void k_t0(const void* src, float2* dst, const float* __restrict__ params, int d) {
  const unsigned tt = blockIdx.x;   // 0..1023 : bits 6..15 of index
  const unsigned b  = threadIdx.x;  // 0..127  : batch lane
  float2 a[64];
  if (FIRST) {
    const float* in = (const float*)src;
    const float4* in4 = (const float4*)(in + (size_t)b * DIMQ + (size_t)tt * 64);
#pragma unroll
    for (int j = 0; j < 16; ++j) {
      float4 q = in4[j];
      a[4 * j + 0] = make_float2(q.x, 0.f);
      a[4 * j + 1] = make_float2(q.y, 0.f);
      a[4 * j + 2] = make_float2(q.z, 0.f);
      a[4 * j + 3] = make_float2(q.w, 0.f);
    }
  } else {
    const float2* ps = (const float2*)src;
#pragma unroll
    for (int l = 0; l < 64; ++l)
      a[l] = ps[(size_t)((tt << 6) | l) * BQ + b];
  }
  apply_gate<0>(a, make_u(params, d, 15));
  apply_gate<1>(a, make_u(params, d, 14));
  apply_gate<2>(a, make_u(params, d, 13));
  apply_gate<3>(a, make_u(params, d, 12));
  apply_gate<4>(a, make_u(params, d, 11));
  apply_gate<5>(a, make_u(params, d, 10));
#pragma unroll
  for (int l = 0; l < 64; ++l)
    dst[(size_t)((tt << 6) | l) * BQ + b] = a[l];
}

// ---------------------------------------------------------------------------
// Pass type 1: window bits 6..11 (wires 9..4). In-place.
// ---------------------------------------------------------------------------
__global__ __launch_bounds__(128, 2)
void k_t1(float2* psi, const float* __restrict__ params, int d) {
  const unsigned tt = blockIdx.x;   // low 6 bits -> index bits 0..5; high 4 -> bits 12..15
  const unsigned b  = threadIdx.x;
  float2 a[64];
#pragma unroll
  for (int l = 0; l < 64; ++l) {
    unsigned x = (tt & 63u) | ((unsigned)l << 6) | ((tt >> 6) << 12);
    a[l] = psi[(size_t)x * BQ + b];
  }
  apply_gate<0>(a, make_u(params, d, 9));
  apply_gate<1>(a, make_u(params, d, 8));
  apply_gate<2>(a, make_u(params, d, 7));
  apply_gate<3>(a, make_u(params, d, 6));
  apply_gate<4>(a, make_u(params, d, 5));
  apply_gate<5>(a, make_u(params, d, 4));
#pragma unroll
  for (int l = 0; l < 64; ++l) {
    unsigned x = (tt & 63u) | ((unsigned)l << 6) | ((tt >> 6) << 12);
    psi[(size_t)x * BQ + b] = a[l];
  }
}

// ---------------------------------------------------------------------------
// Pass type 2: window bits 10..15, gates on bits 12..15 (wires 3..0), then the
// CNOT ring applied as a free store-side permutation. EPI variant instead
// computes |psi|^2 and per-wire Z partial sums (signs from the permuted
// logical index; static part folds at compile time).
// ---------------------------------------------------------------------------
template <bool EPI>
__global__ __launch_bounds__(128, 2)
void k_t2(const float2* __restrict__ src, float2* dst, float* partials,
          const float* __restrict__ params, int d) {
  const unsigned tt = blockIdx.x;   // index bits 0..9
  const unsigned b  = threadIdx.x;
  float2 a[64];
#pragma unroll
  for (int l = 0; l < 64; ++l)
    a[l] = src[(size_t)(tt | ((unsigned)l << 10)) * BQ + b];
  apply_gate<2>(a, make_u(params, d, 3));
  apply_gate<3>(a, make_u(params, d, 2));
  apply_gate<4>(a, make_u(params, d, 1));
  apply_gate<5>(a, make_u(params, d, 0));
  const unsigned rtt = ring_map(tt);   // linear: full map = rtt ^ RB.v[l]
  if (!EPI) {
#pragma unroll
    for (int l = 0; l < 64; ++l)
      dst[(size_t)(rtt ^ RB.v[l]) * BQ + b] = a[l];
  } else {
    float acc[16];
#pragma unroll
    for (int w = 0; w < 16; ++w) acc[w] = 0.f;
#pragma unroll
    for (int l = 0; l < 64; ++l) {
      float p = fmaf(a[l].x, a[l].x, a[l].y * a[l].y);
#pragma unroll
      for (int w = 0; w < 16; ++w) {
        // static sign from RB.v[l]; runtime (block-uniform) sign from rtt
        acc[w] += ((RB.v[l] >> (15 - w)) & 1u) ? -p : p;
      }
    }
#pragma unroll
    for (int w = 0; w < 16; ++w) {
      float v = ((rtt >> (15 - w)) & 1u) ? -acc[w] : acc[w];
      partials[((size_t)tt * 16 + w) * BQ + b] = v;
    }
  }
}

// ---------------------------------------------------------------------------
// Final reduction over the 1024 tiles + linear head. One block per batch elem.
// ---------------------------------------------------------------------------
__global__ __launch_bounds__(256)
void k_reduce(const float* __restrict__ partials, const float* __restrict__ hw,
              const float* __restrict__ hb, float* __restrict__ out) {
  const int bq  = blockIdx.x;        // batch element
  const int tid = threadIdx.x;       // = i*16 + w
  const int w   = tid & 15;
  const int i   = tid >> 4;
  float s = 0.f;
  for (int c = 0; c < 64; ++c) {
    int t_ = i * 64 + c;
    s += partials[((size_t)t_ * 16 + w) * BQ + bq];
  }
  __shared__ float red[256];
  __shared__ float feats[16];
  red[tid] = s;
  __syncthreads();
  if (tid < 16) {
    float f = 0.f;
    for (int i2 = 0; i2 < 16; ++i2) f += red[i2 * 16 + tid];
    feats[tid] = f;
  }
  __syncthreads();
  if (tid == 0) {
    float o = hb[0];
    for (int w2 = 0; w2 < 16; ++w2) o = fmaf(feats[w2], hw[w2], o);
    out[bq] = o;
  }
}

extern "C" void kernel_launch(void* const* d_in, const int* in_sizes, int n_in,
                              void* d_out, int out_size, void* d_ws, size_t ws_size,
                              hipStream_t stream) {
  const float* state  = (const float*)d_in[0];   // (128, 65536) f32
  const float* params = (const float*)d_in[1];   // (3, 16, 2)   f32
  const float* head_w = (const float*)d_in[2];   // (1, 16)      f32
  const float* head_b = (const float*)d_in[3];   // (1,)         f32
  float* out = (float*)d_out;                    // (128,)       f32

  float2* bufA = (float2*)d_ws;                           // 64 MB
  float2* bufB = bufA + (size_t)DIMQ * BQ;                // 64 MB
  float*  partials = (float*)(bufB + (size_t)DIMQ * BQ);  // 8 MB

  const dim3 g(1024), blk(128);
  // layer 0
  k_t0<true ><<<g, blk, 0, stream>>>(state, bufA, params, 0);
  k_t1       <<<g, blk, 0, stream>>>(bufA, params, 0);
  k_t2<false><<<g, blk, 0, stream>>>(bufA, bufB, nullptr, params, 0);
  // layer 1
  k_t0<false><<<g, blk, 0, stream>>>(bufB, bufB, params, 1);
  k_t1       <<<g, blk, 0, stream>>>(bufB, params, 1);
  k_t2<false><<<g, blk, 0, stream>>>(bufB, bufA, nullptr, params, 1);
  // layer 2
  k_t0<false><<<g, blk, 0, stream>>>(bufA, bufA, params, 2);
  k_t1       <<<g, blk, 0, stream>>>(bufA, params, 2);
  k_t2<true ><<<g, blk, 0, stream>>>(bufA, nullptr, partials, params, 2);
  // epilogue
  k_reduce<<<dim3(128), dim3(256), 0, stream>>>(partials, head_w, head_b, out);
}

// Round 2
// 298.862 us; speedup vs baseline: 1.7431x; 1.7431x over previous
//
#include <hip/hip_runtime.h>
#include <hip/hip_fp16.h>

#define DIMQ 65536
#define BQ 128

// ---------------------------------------------------------------------------
// CNOT ring as a GF(2)-linear index permutation (verified round 1, absmax 0).
// ---------------------------------------------------------------------------
__host__ __device__ constexpr unsigned ring_map(unsigned x) {
  for (int bc = 15; bc >= 1; --bc) x ^= ((x >> bc) & 1u) << (bc - 1);
  x ^= (x & 1u) << 15;
  return x;
}

struct RBTab32 { unsigned v[32]; };
__host__ __device__ constexpr RBTab32 make_rb32() {
  RBTab32 t{};
  for (int r = 0; r < 32; ++r) t.v[r] = ring_map(((unsigned)r) << 11);
  return t;
}
__device__ constexpr RBTab32 RB32 = make_rb32();

// Fused U = RZ(phi) @ RY(theta), 8 floats, wave-uniform.
struct U2 { float r00, i00, r01, i01, r10, i10, r11, i11; };

// Prep kernel: precompute all DEPTH*16 U matrices (kills sincosf in hot loops).
__global__ void k_prep(const float* __restrict__ params, float* __restrict__ uc) {
  int g = threadIdx.x;              // 0..47 = d*16+w
  if (g >= 48) return;
  float th = 0.5f * params[g * 2 + 0];
  float ph = 0.5f * params[g * 2 + 1];
  float st, ct, sp, cp;
  __sincosf(th, &st, &ct);
  __sincosf(ph, &sp, &cp);
  float* u = uc + g * 8;
  u[0] =  cp * ct; u[1] = -sp * ct;   // em*cth
  u[2] = -cp * st; u[3] =  sp * st;   // -em*sth
  u[4] =  cp * st; u[5] =  sp * st;   // ep*sth
  u[6] =  cp * ct; u[7] =  sp * ct;   // ep*cth
}

__device__ inline U2 load_u(const float* __restrict__ uc, int d, int w) {
  const float* u = uc + (d * 16 + w) * 8;
  U2 r;
  r.r00 = u[0]; r.i00 = u[1]; r.r01 = u[2]; r.i01 = u[3];
  r.r10 = u[4]; r.i10 = u[5]; r.r11 = u[6]; r.i11 = u[7];
  return r;
}

// ---------------------------------------------------------------------------
// Cross-lane xor exchange: DPP for 1,2; ds_swizzle for 4,8,16; shfl for 32.
// ---------------------------------------------------------------------------
template <int MASK>
__device__ inline float lane_xor_f(float v) {
  if constexpr (MASK == 1) {
    return __int_as_float(__builtin_amdgcn_update_dpp(
        0, __float_as_int(v), 0xB1 /*quad_perm [1,0,3,2]*/, 0xF, 0xF, true));
  } else if constexpr (MASK == 2) {
    return __int_as_float(__builtin_amdgcn_update_dpp(
        0, __float_as_int(v), 0x4E /*quad_perm [2,3,0,1]*/, 0xF, 0xF, true));
  } else if constexpr (MASK == 4 || MASK == 8 || MASK == 16) {
    return __int_as_float(__builtin_amdgcn_ds_swizzle(
        __float_as_int(v), (MASK << 10) | 0x1F));
  } else {
    return __shfl_xor(v, MASK, 64);
  }
}

// Gate on a LANE bit (dim bit lives in the lane index).
template <int MASK>
__device__ inline void lane_gate(float2 (&a)[32], const U2 u, int lane) {
  const bool hi = (lane & MASK) != 0;
  const float c0r = hi ? u.r11 : u.r00, c0i = hi ? u.i11 : u.i00;
  const float c1r = hi ? u.r10 : u.r01, c1i = hi ? u.i10 : u.i01;
#pragma unroll
  for (int l = 0; l < 32; ++l) {
    const float px = lane_xor_f<MASK>(a[l].x);
    const float py = lane_xor_f<MASK>(a[l].y);
    const float ax = a[l].x, ay = a[l].y;
    a[l].x = fmaf(c0r, ax, fmaf(-c0i, ay, fmaf(c1r, px, -c1i * py)));
    a[l].y = fmaf(c0r, ay, fmaf( c0i, ax, fmaf(c1r, py,  c1i * px)));
  }
}

// Gate on a REGISTER bit K (0..4) of the 32-amplitude tile.
template <int K>
__device__ inline void reg_gate(float2 (&a)[32], const U2 u) {
#pragma unroll
  for (int l = 0; l < 32; ++l) {
    if (l & (1 << K)) continue;
    const int p = l | (1 << K);
    const float a0r = a[l].x, a0i = a[l].y, a1r = a[p].x, a1i = a[p].y;
    a[l].x = fmaf(u.r00, a0r, fmaf(-u.i00, a0i, fmaf(u.r01, a1r, -u.i01 * a1i)));
    a[l].y = fmaf(u.r00, a0i, fmaf( u.i00, a0r, fmaf(u.r01, a1i,  u.i01 * a1r)));
    a[p].x = fmaf(u.r10, a0r, fmaf(-u.i10, a0i, fmaf(u.r11, a1r, -u.i11 * a1i)));
    a[p].y = fmaf(u.r10, a0i, fmaf( u.i10, a0r, fmaf(u.r11, a1i,  u.i11 * a1r)));
  }
}

// ---------------------------------------------------------------------------
// Pass A: wires 15..10 on lane bits 0..5, wires 9..5 on reg bits (dim 6..10).
// Block bits = dim 11..15. In-place safe (wave touches only its own amps).
// ---------------------------------------------------------------------------
template <bool FIRST>
__global__ __launch_bounds__(256, 4)
void pass_a(const float* __restrict__ in0, const __half2* __restrict__ pin,
            __half2* __restrict__ pout, const float* __restrict__ uc, int d) {
  const int tid  = blockIdx.x * 256 + threadIdx.x;
  const int lane = threadIdx.x & 63;
  const int wave = tid >> 6;
  const int b = wave >> 5;
  const int t = wave & 31;                      // dim bits 11..15
  const size_t base = (size_t)b * DIMQ + ((size_t)t << 11);
  float2 a[32];
  if (FIRST) {
#pragma unroll
    for (int r = 0; r < 32; ++r)
      a[r] = make_float2(in0[base + (r << 6) + lane], 0.f);
  } else {
#pragma unroll
    for (int r = 0; r < 32; ++r)
      a[r] = __half22float2(pin[base + (r << 6) + lane]);
  }
  // lane-bit gates: dim bit k = lane bit k, wire = 15-k
  lane_gate<1 >(a, load_u(uc, d, 15), lane);
  lane_gate<2 >(a, load_u(uc, d, 14), lane);
  lane_gate<4 >(a, load_u(uc, d, 13), lane);
  lane_gate<8 >(a, load_u(uc, d, 12), lane);
  lane_gate<16>(a, load_u(uc, d, 11), lane);
  lane_gate<32>(a, load_u(uc, d, 10), lane);
  // reg-bit gates: dim bit 6+k, wire = 9-k
  reg_gate<0>(a, load_u(uc, d, 9));
  reg_gate<1>(a, load_u(uc, d, 8));
  reg_gate<2>(a, load_u(uc, d, 7));
  reg_gate<3>(a, load_u(uc, d, 6));
  reg_gate<4>(a, load_u(uc, d, 5));
#pragma unroll
  for (int r = 0; r < 32; ++r)
    pout[base + (r << 6) + lane] = __float22half2_rn(a[r]);
}

// ---------------------------------------------------------------------------
// Pass B: wires 4..0 on reg bits (dim 11..15), block bits = dim 6..10, lane
// bits = dim 0..5. Then CNOT ring as store-side permutation (layers 0,1) or
// fused |psi|^2 + Z-sign epilogue (layer 2). NOT in-place (ring permutes).
// ---------------------------------------------------------------------------
template <bool EPI>
__global__ __launch_bounds__(256, 4)
void pass_b(const __half2* __restrict__ pin, __half2* __restrict__ pout,
            float* __restrict__ partials, const float* __restrict__ uc, int d) {
  const int tid  = blockIdx.x * 256 + threadIdx.x;
  const int lane = threadIdx.x & 63;
  const int wave = tid >> 6;
  const int b = wave >> 5;
  const int t = wave & 31;                      // dim bits 6..10
  const unsigned xb = ((unsigned)t << 6) | (unsigned)lane;  // dim bits 0..10
  const size_t base = (size_t)b * DIMQ;
  float2 a[32];
#pragma unroll
  for (int r = 0; r < 32; ++r)
    a[r] = __half22float2(pin[base + xb + ((size_t)r << 11)]);
  // reg-bit gates: dim bit 11+k, wire = 4-k
  reg_gate<0>(a, load_u(uc, d, 4));
  reg_gate<1>(a, load_u(uc, d, 3));
  reg_gate<2>(a, load_u(uc, d, 2));
  reg_gate<3>(a, load_u(uc, d, 1));
  reg_gate<4>(a, load_u(uc, d, 0));
  const unsigned yb = ring_map(xb);             // linear: y = yb ^ RB32.v[r]
  if (!EPI) {
#pragma unroll
    for (int r = 0; r < 32; ++r)
      pout[base + (yb ^ RB32.v[r])] = __float22half2_rn(a[r]);
  } else {
    float acc[16];
#pragma unroll
    for (int w = 0; w < 16; ++w) acc[w] = 0.f;
#pragma unroll
    for (int r = 0; r < 32; ++r) {
      const float p = fmaf(a[r].x, a[r].x, a[r].y * a[r].y);
      const unsigned y = yb ^ RB32.v[r];
#pragma unroll
      for (int w = 0; w < 16; ++w)
        acc[w] += ((y >> (15 - w)) & 1u) ? -p : p;
    }
#pragma unroll
    for (int w = 0; w < 16; ++w) {
      float s = acc[w];
      s += __shfl_xor(s, 1, 64);
      s += __shfl_xor(s, 2, 64);
      s += __shfl_xor(s, 4, 64);
      s += __shfl_xor(s, 8, 64);
      s += __shfl_xor(s, 16, 64);
      s += __shfl_xor(s, 32, 64);
      acc[w] = s;
    }
    if (lane == 0) {
      float* dst = partials + ((size_t)b * 32 + t) * 16;
#pragma unroll
      for (int w = 0; w < 16; ++w) dst[w] = acc[w];
    }
  }
}

// ---------------------------------------------------------------------------
// Head: reduce 32 tiles per (batch, wire), apply linear head.
// ---------------------------------------------------------------------------
__global__ __launch_bounds__(256)
void k_head(const float* __restrict__ partials, const float* __restrict__ hw,
            const float* __restrict__ hb, float* __restrict__ out) {
  const int b = blockIdx.x;
  const int t = threadIdx.x;       // 0..255
  const int w = t & 15;
  const int i = t >> 4;            // tile 0..15 (+16)
  float s = partials[((size_t)b * 32 + i) * 16 + w] +
            partials[((size_t)b * 32 + i + 16) * 16 + w];
  __shared__ float red[256];
  __shared__ float feats[16];
  red[t] = s;
  __syncthreads();
  if (t < 16) {
    float f = 0.f;
    for (int j = 0; j < 16; ++j) f += red[j * 16 + t];
    feats[t] = f;
  }
  __syncthreads();
  if (t == 0) {
    float o = hb[0];
    for (int w2 = 0; w2 < 16; ++w2) o = fmaf(feats[w2], hw[w2], o);
    out[b] = o;
  }
}

extern "C" void kernel_launch(void* const* d_in, const int* in_sizes, int n_in,
                              void* d_out, int out_size, void* d_ws, size_t ws_size,
                              hipStream_t stream) {
  const float* state  = (const float*)d_in[0];   // (128, 65536) f32
  const float* params = (const float*)d_in[1];   // (3, 16, 2)   f32
  const float* head_w = (const float*)d_in[2];   // (1, 16)      f32
  const float* head_b = (const float*)d_in[3];   // (1,)         f32
  float* out = (float*)d_out;                    // (128,)       f32

  __half2* bufA = (__half2*)d_ws;                          // 32 MB
  __half2* bufB = bufA + (size_t)DIMQ * BQ / 1;            // (DIMQ*BQ half2 = 32 MB)
  float*   partials = (float*)(bufB + (size_t)DIMQ * BQ);  // 256 KB
  float*   uc = partials + (size_t)BQ * 32 * 16;           // 1.5 KB

  k_prep<<<dim3(1), dim3(64), 0, stream>>>(params, uc);

  const dim3 g(1024), blk(256);
  // layer 0
  pass_a<true ><<<g, blk, 0, stream>>>(state, nullptr, bufA, uc, 0);
  pass_b<false><<<g, blk, 0, stream>>>(bufA, bufB, nullptr, uc, 0);
  // layer 1
  pass_a<false><<<g, blk, 0, stream>>>(nullptr, bufB, bufB, uc, 1);
  pass_b<false><<<g, blk, 0, stream>>>(bufB, bufA, nullptr, uc, 1);
  // layer 2
  pass_a<false><<<g, blk, 0, stream>>>(nullptr, bufA, bufA, uc, 2);
  pass_b<true ><<<g, blk, 0, stream>>>(bufA, nullptr, partials, uc, 2);
  // head
  k_head<<<dim3(128), blk, 0, stream>>>(partials, head_w, head_b, out);
}